// Round 2
// baseline (242.561 us; speedup 1.0000x reference)
//
#include <hip/hip_runtime.h>

#define PI_F 3.14159f

// ---------------------------------------------------------------------------
// Kernel A: per-batch MLP head -> per-channel PRE-SCALED affine params.
// 4 batches per block, 256 threads. Phase 1 keeps para in registers and
// broadcasts with v_readlane (no LDS). params layout: [B][20][8] =
// (P0..P5, 0, 0):  ix = P0*X + P1*Y + P2 ; iy = P3*X + P4*Y + P5
// with grid_sample *9+8.5 scaling and the +1 LDS-pad shift folded in.
// ---------------------------------------------------------------------------
__global__ __launch_bounds__(256) void params_kernel(
    const float* __restrict__ pc, const float* __restrict__ W1, const float* __restrict__ b1,
    const float* __restrict__ Ws, const float* __restrict__ bs,
    const float* __restrict__ Wr, const float* __restrict__ br,
    const float* __restrict__ Wt, const float* __restrict__ bt,
    float* __restrict__ params)
{
    __shared__ float hbuf[4][260];
    __shared__ float raw[4][80];

    const int t    = threadIdx.x;
    const int lane = t & 63;
    const int b0   = blockIdx.x * 4;

    float pval[4][4];
    #pragma unroll
    for (int g = 0; g < 4; ++g)
        #pragma unroll
        for (int c = 0; c < 4; ++c)
            pval[g][c] = pc[(size_t)(b0 + g) * 256 + c * 64 + lane];

    float acc[4];
    #pragma unroll
    for (int g = 0; g < 4; ++g) acc[g] = b1[t];

    #pragma unroll
    for (int c = 0; c < 4; ++c) {
        for (int kk = 0; kk < 64; ++kk) {
            float w = W1[(c * 64 + kk) * 256 + t];
            #pragma unroll
            for (int g = 0; g < 4; ++g) {
                float pk = __int_as_float(
                    __builtin_amdgcn_readlane(__float_as_int(pval[g][c]), kk));
                acc[g] = fmaf(pk, w, acc[g]);
            }
        }
    }
    #pragma unroll
    for (int g = 0; g < 4; ++g) hbuf[g][t] = fmaxf(acc[g], 0.0f);
    __syncthreads();

    for (int task = t; task < 320; task += 256) {
        int g   = task / 80;
        int col = task - g * 80;
        const float* Wcol;
        float bias;
        int stride;
        if (col < 20)      { Wcol = Ws + col;        bias = bs[col];      stride = 20; }
        else if (col < 40) { Wcol = Wr + (col - 20); bias = br[col - 20]; stride = 20; }
        else               { Wcol = Wt + (col - 40); bias = bt[col - 40]; stride = 40; }
        const float4* h4 = (const float4*)hbuf[g];
        float a = bias;
        for (int k4 = 0; k4 < 64; ++k4) {
            float4 h = h4[k4];
            int k = k4 * 4;
            a = fmaf(h.x, Wcol[k * stride], a);
            a = fmaf(h.y, Wcol[(k + 1) * stride], a);
            a = fmaf(h.z, Wcol[(k + 2) * stride], a);
            a = fmaf(h.w, Wcol[(k + 3) * stride], a);
        }
        raw[g][col] = a;
    }
    __syncthreads();

    for (int task = t; task < 80; task += 256) {
        int g = task / 20;
        int f = task - g * 20;
        float sc  = 2.0f / (1.0f + expf(-raw[g][f]));
        float ang = PI_F * tanhf(raw[g][20 + f]);
        float tx  = tanhf(raw[g][40 + 2 * f]);
        float ty  = tanhf(raw[g][40 + 2 * f + 1]);
        float c = cosf(ang), s = sinf(ang);
        float* o = params + ((size_t)(b0 + g) * 20 + f) * 8;
        o[0] = 9.0f * sc * c;  o[1] = -9.0f * sc * s;  o[2] = fmaf(9.0f, tx, 9.5f);
        o[3] = 9.0f * sc * s;  o[4] =  9.0f * sc * c;  o[5] = fmaf(9.0f, ty, 9.5f);
        o[6] = 0.0f;           o[7] = 0.0f;
    }
}

// ---------------------------------------------------------------------------
// Kernel B v3: ONE WAVE owns ONE (batch, channel). The wave z-blends its
// channel's 2 slices into a private padded [20][20] LDS image (+24-float
// tail) and samples its 324 outputs — all wave-synchronous, ZERO
// __syncthreads(). Block = 4 waves = 4 consecutive channels of one batch.
// LDS = 4*424*4 = 6784 B -> occupancy is wave-limited at 8 blocks/CU =
// 32/32 waves (100%). All 64 lanes active (324 = 5*64 + 4 tail).
// Zero-padding via coordinate clamp (weight-0 taps at clamp boundary);
// pad border + tail are zeroed so weight-0 overreads stay finite.
// ---------------------------------------------------------------------------
__global__ __launch_bounds__(256, 8) void sample_kernel(
    const float* __restrict__ fmap, const float* __restrict__ params,
    float* __restrict__ out)
{
    __shared__ __align__(16) float lds[4][424];

    const int t    = threadIdx.x;
    const int lane = t & 63;
    const int w    = t >> 6;
    const int bid  = blockIdx.x;
    const int b    = bid / 5;
    const int c    = (bid - b * 5) * 4 + w;     // channel 0..19
    float* wv = lds[w];

    // --- zero the 76 pad-border cells + 24-float tail (100 cells, 2 rounds)
    #pragma unroll
    for (int r = 0; r < 2; ++r) {
        int i = r * 64 + lane;
        if (i < 100) {
            int idx;
            if (i < 20)      idx = i;                                  // row 0
            else if (i < 40) idx = 380 + (i - 20);                     // row 19
            else if (i < 76) {                                          // cols 0,19
                int q = i - 40;
                int y = 1 + (q < 18 ? q : q - 18);
                idx = y * 20 + (q < 18 ? 0 : 19);
            } else idx = 400 + (i - 76);                                // tail
            wv[idx] = 0.0f;
        }
    }

    // --- z-blend weights for this channel (iz = (40c-19)/38; exact at ±.5)
    const float izf = (40.0f * (float)c - 19.0f) * (1.0f / 38.0f);
    const float fz0 = floorf(izf);
    const int   z0  = (int)fz0;
    const float wzB = izf - fz0;
    const bool  v0  = (z0 >= 0);
    const bool  v1  = (z0 + 1 <= 19);
    const float ew0 = v0 ? (1.0f - wzB) : 0.0f;
    const float ew1 = v1 ? wzB : 0.0f;
    const float* fb = fmap + (size_t)b * 6480;
    const float* s0 = fb + (v0 ? z0 : 0) * 324;
    const float* s1 = fb + (v1 ? z0 + 1 : 19) * 324;

    // --- stage: blend 2 slices -> padded interior (wave-private, no barrier)
    #pragma unroll
    for (int it = 0; it < 6; ++it) {
        int i = it * 64 + lane;
        if (i < 324) {
            float a  = s0[i];
            float bb = s1[i];
            int y = i / 18, x = i - y * 18;
            wv[(y + 1) * 20 + (x + 1)] = fmaf(a, ew0, bb * ew1);
        }
    }

    // --- affine params for this channel (wave-uniform address)
    const float* pp = params + ((size_t)b * 20 + c) * 8;
    const float4 pA = *(const float4*)pp;
    const float2 pB = *(const float2*)(pp + 4);

    // --- sample 324 points (ds_write -> ds_read ordered by lgkmcnt in-wave)
    float* ob = out + (size_t)b * 6480 + c * 324;
    #pragma unroll
    for (int it = 0; it < 6; ++it) {
        int i = it * 64 + lane;
        if (i < 324) {
            int y = i / 18, x = i - y * 18;
            float X = (float)x * (2.0f / 17.0f) - 1.0f;
            float Y = (float)y * (2.0f / 17.0f) - 1.0f;
            float ix = fmaf(pA.x, X, fmaf(pA.y, Y, pA.z));
            float iy = fmaf(pA.w, X, fmaf(pB.x, Y, pB.y));
            ix = fminf(fmaxf(ix, 0.0f), 19.0f);
            iy = fminf(fmaxf(iy, 0.0f), 19.0f);
            float fx = floorf(ix), fy = floorf(iy);
            float u1 = ix - fx, vv = iy - fy;
            const float* s = wv + ((int)fy * 20 + (int)fx);
            float t00 = s[0], t01 = s[1], t10 = s[20], t11 = s[21];
            float u0 = 1.0f - u1, vc = 1.0f - vv;
            float r = fmaf(fmaf(t01, u1, t00 * u0), vc,
                           fmaf(t11, u1, t10 * u0) * vv);
            ob[i] = r;
        }
    }
}

extern "C" void kernel_launch(void* const* d_in, const int* in_sizes, int n_in,
                              void* d_out, int out_size, void* d_ws, size_t ws_size,
                              hipStream_t stream)
{
    const float* fmap = (const float*)d_in[0];
    const float* pc   = (const float*)d_in[1];
    const float* W1   = (const float*)d_in[2];
    const float* b1   = (const float*)d_in[3];
    const float* Ws   = (const float*)d_in[4];
    const float* bs   = (const float*)d_in[5];
    const float* Wr   = (const float*)d_in[6];
    const float* br   = (const float*)d_in[7];
    const float* Wt   = (const float*)d_in[8];
    const float* bt   = (const float*)d_in[9];
    float* out    = (float*)d_out;
    float* params = (float*)d_ws;     // B*20*8 floats

    const int B = in_sizes[0] / (20 * 18 * 18);   // 4096

    params_kernel<<<B / 4, 256, 0, stream>>>(pc, W1, b1, Ws, bs, Wr, br, Wt, bt, params);
    sample_kernel<<<B * 5, 256, 0, stream>>>(fmap, params, out);
}